// Round 9
// baseline (205.327 us; speedup 1.0000x reference)
//
#include <hip/hip_runtime.h>
#include <stdint.h>

typedef unsigned short u16;
using short8 = __attribute__((ext_vector_type(8))) short;   // 8 x bf16 (4 VGPRs)
using f32x4  = __attribute__((ext_vector_type(4))) float;   // MFMA accumulator

typedef __attribute__((address_space(1))) unsigned int gu32;
typedef __attribute__((address_space(3))) unsigned int lu32;

// async 16B global->LDS. LDS dst = wave-uniform base + lane*16 (m97/m104).
__device__ __forceinline__ void gl2lds16(const u16* g, u16* lds_wave_base) {
    __builtin_amdgcn_global_load_lds(
        (gu32*)(uintptr_t)(const void*)g,
        (lu32*)(uint32_t)(uintptr_t)(void*)lds_wave_base,
        16, 0, 0);
}

__device__ inline float bf2f(u16 u) {
    union { unsigned int i; float f; } v;
    v.i = ((unsigned int)u) << 16;
    return v.f;
}
__device__ inline u16 f2bf(float f) {          // RNE
    union { float f; unsigned int i; } v;
    v.f = f;
    unsigned int x = v.i;
    return (u16)((x + 0x7fffu + ((x >> 16) & 1u)) >> 16);
}
__device__ inline u16 f2bf_trunc(float f) {    // truncate (1 VALU op)
    union { float f; unsigned int i; } v;
    v.f = f;
    return (u16)(v.i >> 16);
}

// ---------------------------------------------------------------------------
// Kernel 1 (prep, single launch): z=0..3 transpose+cvt the 4 weight matrices;
// z=4 fills the RoPE (cos,sin) fp32 table; z=5..8 convert x fp32->bf16.
// ---------------------------------------------------------------------------
__global__ __launch_bounds__(256) void prep(
    const float* __restrict__ x, u16* __restrict__ xb,
    const float* __restrict__ w0, const float* __restrict__ w1,
    const float* __restrict__ w2, const float* __restrict__ w3,
    u16* __restrict__ t0, u16* __restrict__ t1,
    u16* __restrict__ t2, u16* __restrict__ t3,
    float2* __restrict__ tab)
{
    int tx = threadIdx.x, ty = threadIdx.y;              // (32, 8)
    int tid = ty * 32 + tx;
    int z = blockIdx.z;
    if (z == 4) {
        int bidx = blockIdx.y * 32 + blockIdx.x;
        if (bidx < 256) {
            int idx = bidx * 256 + tid;                  // 0..65535
            int pos = idx >> 5, pi = idx & 31;
            const float l2_10000_over_32 = 0.41524101186f;   // log2(10000)/32
            float ang = (float)pos *
                __builtin_amdgcn_exp2f(-(float)pi * l2_10000_over_32);
            float sn, cs;
            __sincosf(ang, &sn, &cs);
            tab[idx] = make_float2(cs, sn);
        }
        return;
    }
    if (z >= 5) {
        int i = (((z - 5) * 1024 + blockIdx.y * 32 + blockIdx.x) * 256 + tid) * 4;
        float4 v = *(const float4*)(x + i);
        ushort4 o;
        o.x = f2bf(v.x); o.y = f2bf(v.y); o.z = f2bf(v.z); o.w = f2bf(v.w);
        *(ushort4*)(xb + i) = o;
        return;
    }
    __shared__ u16 tile[32][33];
    const float* src; u16* dst;
    switch (z) {
        case 0:  src = w0; dst = t0; break;
        case 1:  src = w1; dst = t1; break;
        case 2:  src = w2; dst = t2; break;
        default: src = w3; dst = t3; break;
    }
    int c0 = blockIdx.x * 32, r0 = blockIdx.y * 32;
    #pragma unroll
    for (int i = 0; i < 4; i++)
        tile[ty + i * 8][tx] = f2bf(src[(size_t)(r0 + ty + i * 8) * 1024 + c0 + tx]);
    __syncthreads();
    #pragma unroll
    for (int i = 0; i < 4; i++)
        dst[(size_t)(c0 + ty + i * 8) * 1024 + r0 + tx] = tile[tx][ty + i * 8];
}

// ---------------------------------------------------------------------------
// Kernel 2a: fused QKV GEMM, BK=64 (half the barriers of BK=32).
// A: 4096x1024 bf16 (x), Bt: 3072x1024 stacked [Wq^T; Wk^T; Wv^T].
// Q/K epilogue: table-based RoPE (table read straight from L1/L2).
// V epilogue: transpose via LDS bounce, write VT[bh][64][2048] directly
// (kills the separate transpose_v kernel + 16 MB HBM round-trip).
// Q scaled by 1/sqrt(1024)*log2(e) (softmax scale + exp->exp2 fold).
// ---------------------------------------------------------------------------
__global__ __launch_bounds__(256) void gemm_qkv(
    const u16* __restrict__ A, const u16* __restrict__ Bt,
    const float2* __restrict__ ropetab,
    u16* __restrict__ Qb, u16* __restrict__ Kb, u16* __restrict__ VT)
{
    __shared__ __align__(16) char smem[128 * 136 * 2];  // 34 KB pool
    u16* As = (u16*)smem;                                // 128x64 (16 KB)
    u16* Bs = (u16*)(smem + 16384);                      // 128x64 (16 KB)

    const int tid  = threadIdx.x;
    const int lane = tid & 63;
    const int wid  = tid >> 6;
    const int quad = lane >> 4;
    const int l15  = lane & 15;
    const int wm   = wid >> 1, wn = wid & 1;

    const int m0 = blockIdx.y * 128;
    const int n0 = blockIdx.x * 128;          // 0..2944, global stacked col
    const int mat = n0 >> 10;                 // 0=Q 1=K 2=V
    const int ln0 = n0 & 1023;                // col within that matrix

    f32x4 acc[4][4] = {};

    for (int k0 = 0; k0 < 1024; k0 += 64) {
        #pragma unroll
        for (int it = 0; it < 4; it++) {
            int c   = it * 256 + tid;                // chunk 0..1023 (16B each)
            int row = c >> 3;
            int col = ((c & 7) ^ (row & 7)) * 8;     // swizzled source chunk
            u16* lbA = &As[(size_t)(it * 256 + wid * 64) * 8];
            u16* lbB = &Bs[(size_t)(it * 256 + wid * 64) * 8];
            gl2lds16(&A [(size_t)(m0 + row) * 1024 + k0 + col], lbA);
            gl2lds16(&Bt[(size_t)(n0 + row) * 1024 + k0 + col], lbB);
        }
        __syncthreads();

        #pragma unroll
        for (int s = 0; s < 2; s++) {            // two K=32 steps within BK=64
            short8 a[4], b[4];
            #pragma unroll
            for (int i = 0; i < 4; i++) {
                int ra = wm * 64 + i * 16 + l15;
                int rb = wn * 64 + i * 16 + l15;
                a[i] = *(const short8*)(&As[ra * 64 + (((s * 4 + quad) ^ (ra & 7)) * 8)]);
                b[i] = *(const short8*)(&Bs[rb * 64 + (((s * 4 + quad) ^ (rb & 7)) * 8)]);
            }
            #pragma unroll
            for (int i = 0; i < 4; i++)
                #pragma unroll
                for (int j = 0; j < 4; j++)
                    acc[i][j] = __builtin_amdgcn_mfma_f32_16x16x32_bf16(a[i], b[j], acc[i][j], 0, 0, 0);
        }
        __syncthreads();
    }

    if (mat < 2) {
        u16* C = (mat == 0) ? Qb : Kb;
        const float scale = (mat == 0) ? (0.03125f * 1.44269504f) : 1.0f;
        const int odd = l15 & 1;
        #pragma unroll
        for (int i = 0; i < 4; i++)
            #pragma unroll
            for (int j = 0; j < 4; j++)
                #pragma unroll
                for (int r = 0; r < 4; r++) {
                    int lrow = wm * 64 + i * 16 + quad * 4 + r;
                    int col  = ln0 + wn * 64 + j * 16 + l15;
                    int pos  = (m0 + lrow) & 2047;
                    float v  = acc[i][j][r] * scale;
                    float vp = __shfl_xor(v, 1);     // partner column
                    float2 sc = ropetab[pos * 32 + ((col & 63) >> 1)];
                    float outv = odd ? (v * sc.x + vp * sc.y)
                                     : (v * sc.x - vp * sc.y);
                    C[(size_t)(m0 + lrow) * 1024 + col] = f2bf(outv);
                }
    } else {
        // V: bounce through LDS transposed, then coalesced writes to VT.
        u16* T = (u16*)smem;                    // 128 cols x 136 (pad) rows
        __syncthreads();                        // all waves done with As/Bs
        #pragma unroll
        for (int i = 0; i < 4; i++)
            #pragma unroll
            for (int j = 0; j < 4; j++)
                #pragma unroll
                for (int r = 0; r < 4; r++) {
                    int lrow = wm * 64 + i * 16 + quad * 4 + r;
                    int lcol = wn * 64 + j * 16 + l15;
                    T[lcol * 136 + lrow] = f2bf(acc[i][j][r]);
                }
        __syncthreads();
        int bb2 = m0 >> 11, pos0 = m0 & 2047;
        #pragma unroll
        for (int itc = 0; itc < 8; itc++) {
            int c  = itc * 256 + tid;           // 0..2047 chunks of 8 u16
            int ch = c >> 4;                    // 0..127 (2 heads x 64 ch)
            int px = (c & 15) * 8;
            int head = (ln0 + ch) >> 6;
            size_t dst = ((size_t)(bb2 * 16 + head) * 64 + (ch & 63)) * 2048
                         + pos0 + px;
            *(uint4*)(&VT[dst]) = *(const uint4*)(&T[ch * 136 + px]);
        }
    }
}

// ---------------------------------------------------------------------------
// Kernel 2b: out-projection GEMM, BK=64, fp32 output to d_out.
// ---------------------------------------------------------------------------
__global__ __launch_bounds__(256) void gemm_out(
    const u16* __restrict__ A, const u16* __restrict__ Bt, float* __restrict__ C)
{
    __shared__ __align__(16) u16 As[128 * 64];
    __shared__ __align__(16) u16 Bs[128 * 64];

    const int tid  = threadIdx.x;
    const int lane = tid & 63;
    const int wid  = tid >> 6;
    const int quad = lane >> 4;
    const int l15  = lane & 15;
    const int wm   = wid >> 1, wn = wid & 1;

    const int m0 = blockIdx.y * 128;
    const int n0 = blockIdx.x * 128;

    f32x4 acc[4][4] = {};

    for (int k0 = 0; k0 < 1024; k0 += 64) {
        #pragma unroll
        for (int it = 0; it < 4; it++) {
            int c   = it * 256 + tid;
            int row = c >> 3;
            int col = ((c & 7) ^ (row & 7)) * 8;
            u16* lbA = &As[(size_t)(it * 256 + wid * 64) * 8];
            u16* lbB = &Bs[(size_t)(it * 256 + wid * 64) * 8];
            gl2lds16(&A [(size_t)(m0 + row) * 1024 + k0 + col], lbA);
            gl2lds16(&Bt[(size_t)(n0 + row) * 1024 + k0 + col], lbB);
        }
        __syncthreads();

        #pragma unroll
        for (int s = 0; s < 2; s++) {
            short8 a[4], b[4];
            #pragma unroll
            for (int i = 0; i < 4; i++) {
                int ra = wm * 64 + i * 16 + l15;
                int rb = wn * 64 + i * 16 + l15;
                a[i] = *(const short8*)(&As[ra * 64 + (((s * 4 + quad) ^ (ra & 7)) * 8)]);
                b[i] = *(const short8*)(&Bs[rb * 64 + (((s * 4 + quad) ^ (rb & 7)) * 8)]);
            }
            #pragma unroll
            for (int i = 0; i < 4; i++)
                #pragma unroll
                for (int j = 0; j < 4; j++)
                    acc[i][j] = __builtin_amdgcn_mfma_f32_16x16x32_bf16(a[i], b[j], acc[i][j], 0, 0, 0);
        }
        __syncthreads();
    }

    #pragma unroll
    for (int i = 0; i < 4; i++)
        #pragma unroll
        for (int j = 0; j < 4; j++)
            #pragma unroll
            for (int r = 0; r < 4; r++) {
                int row = m0 + wm * 64 + i * 16 + quad * 4 + r;
                int col = n0 + wn * 64 + j * 16 + l15;
                C[(size_t)row * 1024 + col] = acc[i][j][r];
            }
}

// ---------------------------------------------------------------------------
// Kernel 4: flash attention v7 — v5 shape (8 waves, M=16/wave, best measured)
// + double-buffered Ps (one stripe per 64-key half). The old single-stripe
// version needed a trailing compiler barrier that serialized half-1's
// exp+stores AFTER half-0's PV MFMAs; with 2 stripes the scheduler is free
// to overlap them (VALU under MFMA). LDS 64 KB; grid caps at 2 blocks/CU.
// ---------------------------------------------------------------------------
__global__ __launch_bounds__(512) void attn(
    const u16* __restrict__ Q, const u16* __restrict__ Kb,
    const u16* __restrict__ VT, u16* __restrict__ Y)
{
    __shared__ __align__(16) u16 Ks [128 * 64];    // row=j, col=ch, chunks ^(r&7)
    __shared__ __align__(16) u16 VTs[64 * 128];    // row=ch, col=j, chunks ^(r&15)
    __shared__ __align__(16) u16 Ps [16][16 * 64]; // [wave][half] stripes

    const int tid  = threadIdx.x;
    const int lane = tid & 63, wid = tid >> 6;    // wid 0..7
    const int quad = lane >> 4, l15 = lane & 15;

    const int bh = blockIdx.x;        // 0..31  (XCD-locality: fast axis)
    const int qt = blockIdx.y;        // 0..15, 128 q-rows each
    const int bb = bh >> 4, h = bh & 15;

    const size_t base = ((size_t)bb * 2048) * 1024 + (size_t)h * 64;

    // Q fragments (A-operand: m = lane&15, k = quad*8+j); wave owns 16 rows
    short8 qf[2];
    {
        size_t qrow = (size_t)qt * 128 + wid * 16 + l15;
        const u16* qp = Q + base + qrow * 1024;
        qf[0] = *(const short8*)(qp + quad * 8);
        qf[1] = *(const short8*)(qp + 32 + quad * 8);
    }

    f32x4 o[4] = {};
    float l_r[4] = {0.f, 0.f, 0.f, 0.f};

    for (int j0 = 0; j0 < 2048; j0 += 128) {
        __syncthreads();   // prior tile's fragment reads complete
        #pragma unroll
        for (int it = 0; it < 2; it++) {
            int c = it * 512 + tid;                       // chunk 0..1023
            int rk = c >> 3, ck = ((c & 7)  ^ (rk & 7))  * 8;   // K: 128x64
            int rv = c >> 4, cv = ((c & 15) ^ (rv & 15)) * 8;   // V: 64x128
            u16* lbK = &Ks [(size_t)(it * 512 + wid * 64) * 8];
            u16* lbV = &VTs[(size_t)(it * 512 + wid * 64) * 8];
            gl2lds16(&Kb[base + (size_t)(j0 + rk) * 1024 + ck], lbK);
            gl2lds16(&VT[((size_t)bh * 64 + rv) * 2048 + j0 + cv], lbV);
        }
        __syncthreads();   // drain DMA

        // S: 8 stripes of 16 keys (16x128 logits per wave)
        f32x4 s[8];
        #pragma unroll
        for (int nt = 0; nt < 8; nt++) {
            int R = nt * 16 + l15;
            short8 k0 = *(const short8*)(&Ks[R * 64 + (( quad      ^ (R & 7)) * 8)]);
            short8 k1 = *(const short8*)(&Ks[R * 64 + (((quad + 4) ^ (R & 7)) * 8)]);
            f32x4 z = {};
            z = __builtin_amdgcn_mfma_f32_16x16x32_bf16(qf[0], k0, z, 0, 0, 0);
            z = __builtin_amdgcn_mfma_f32_16x16x32_bf16(qf[1], k1, z, 0, 0, 0);
            s[nt] = z;
        }

        // softmax + PV per 64-key half; Ps double-buffered so half-1's
        // exp/stores can schedule among half-0's PV MFMAs.
        #pragma unroll
        for (int hh = 0; hh < 2; hh++) {
            u16* ps = Ps[wid * 2 + hh];
            #pragma unroll
            for (int n4 = 0; n4 < 4; n4++) {
                int nt = hh * 4 + n4;
                #pragma unroll
                for (int r = 0; r < 4; r++) {
                    float p = __builtin_amdgcn_exp2f(s[nt][r]);
                    l_r[r] += p;
                    int m = quad * 4 + r;
                    int col = n4 * 16 + l15;
                    ps[m * 64 + (((col >> 3) ^ (m & 7)) * 8) + (col & 7)]
                        = f2bf_trunc(p);
                }
            }
            // wave-local RAW fence (DS in-order per wave; stops compiler
            // hoisting the reads above the u16 stores — round-1 lesson)
            asm volatile("s_waitcnt lgkmcnt(0)" ::: "memory");

            short8 pa0 = *(const short8*)(&ps[l15 * 64 + (( quad      ^ (l15 & 7)) * 8)]);
            short8 pa1 = *(const short8*)(&ps[l15 * 64 + (((quad + 4) ^ (l15 & 7)) * 8)]);
            #pragma unroll
            for (int nt = 0; nt < 4; nt++) {
                int R = nt * 16 + l15;
                short8 vb0 = *(const short8*)(&VTs[R * 128 + (((hh * 8 + quad)     ^ (R & 15)) * 8)]);
                short8 vb1 = *(const short8*)(&VTs[R * 128 + (((hh * 8 + quad + 4) ^ (R & 15)) * 8)]);
                o[nt] = __builtin_amdgcn_mfma_f32_16x16x32_bf16(pa0, vb0, o[nt], 0, 0, 0);
                o[nt] = __builtin_amdgcn_mfma_f32_16x16x32_bf16(pa1, vb1, o[nt], 0, 0, 0);
            }
        }
    }

    // one-time row-sum reduction across the 16 lanes of each quad-row
    #pragma unroll
    for (int r = 0; r < 4; r++) {
        l_r[r] += __shfl_xor(l_r[r], 1);
        l_r[r] += __shfl_xor(l_r[r], 2);
        l_r[r] += __shfl_xor(l_r[r], 4);
        l_r[r] += __shfl_xor(l_r[r], 8);
        l_r[r] = 1.0f / l_r[r];
    }

    size_t qrow0 = (size_t)qt * 128 + wid * 16;
    #pragma unroll
    for (int nt = 0; nt < 4; nt++)
        #pragma unroll
        for (int r = 0; r < 4; r++) {
            size_t row = qrow0 + quad * 4 + r;
            Y[base + row * 1024 + nt * 16 + l15] = f2bf(o[nt][r] * l_r[r]);
        }
}

// ---------------------------------------------------------------------------
extern "C" void kernel_launch(void* const* d_in, const int* in_sizes, int n_in,
                              void* d_out, int out_size, void* d_ws, size_t ws_size,
                              hipStream_t stream)
{
    const float* x  = (const float*)d_in[0];
    const float* Wq = (const float*)d_in[1];
    const float* Wk = (const float*)d_in[2];
    const float* Wv = (const float*)d_in[3];
    const float* Wo = (const float*)d_in[4];
    float* out = (float*)d_out;

    char* ws = (char*)d_ws;
    u16*    xb    = (u16*)   (ws + (0ull  << 20));   // 8 MB
    u16*    WqkvT = (u16*)   (ws + (8ull  << 20));   // 6 MB stacked
    u16*    WoT   = (u16*)   (ws + (14ull << 20));   // 2 MB
    u16*    Qb    = (u16*)   (ws + (16ull << 20));   // 8 MB each
    u16*    Kb    = (u16*)   (ws + (24ull << 20));
    u16*    VTb   = (u16*)   (ws + (32ull << 20));   // V transposed per head
    u16*    Yb    = (u16*)   (ws + (40ull << 20));
    float2* tab   = (float2*)(ws + (48ull << 20));   // 512 KB rope table

    // 1) one prep launch: weight transposes (z 0..3), rope table (z 4),
    //    x conversion (z 5..8)
    prep<<<dim3(32, 32, 9), dim3(32, 8), 0, stream>>>(
        x, xb, Wq, Wk, Wv, Wo,
        WqkvT, WqkvT + (1024ull * 1024), WqkvT + (2048ull * 1024), WoT, tab);
    // 2) fused QKV GEMM (+RoPE epilogue, +V^T direct write)
    gemm_qkv<<<dim3(24, 32), 256, 0, stream>>>(xb, WqkvT, tab, Qb, Kb, VTb);
    // 3) flash attention
    attn<<<dim3(32, 16), 512, 0, stream>>>(Qb, Kb, VTb, Yb);
    // 4) output projection (fp32 out)
    gemm_out<<<dim3(8, 32), 256, 0, stream>>>(Yb, WoT, out);
}

// Round 10
// 201.279 us; speedup vs baseline: 1.0201x; 1.0201x over previous
//
#include <hip/hip_runtime.h>
#include <stdint.h>

typedef unsigned short u16;
typedef unsigned int u32;
using short8 = __attribute__((ext_vector_type(8))) short;   // 8 x bf16 (4 VGPRs)
using f32x4  = __attribute__((ext_vector_type(4))) float;
using f32x16 = __attribute__((ext_vector_type(16))) float;  // 32x32 MFMA acc

typedef __attribute__((address_space(1))) unsigned int gu32;
typedef __attribute__((address_space(3))) unsigned int lu32;

// async 16B global->LDS. LDS dst = wave-uniform base + lane*16 (m97/m104).
__device__ __forceinline__ void gl2lds16(const u16* g, u16* lds_wave_base) {
    __builtin_amdgcn_global_load_lds(
        (gu32*)(uintptr_t)(const void*)g,
        (lu32*)(uint32_t)(uintptr_t)(void*)lds_wave_base,
        16, 0, 0);
}

__device__ inline float bf2f(u16 u) {
    union { unsigned int i; float f; } v;
    v.i = ((unsigned int)u) << 16;
    return v.f;
}
__device__ inline u16 f2bf(float f) {          // RNE
    union { float f; unsigned int i; } v;
    v.f = f;
    unsigned int x = v.i;
    return (u16)((x + 0x7fffu + ((x >> 16) & 1u)) >> 16);
}
__device__ inline u32 f2bf_trunc_u32(float f) { // truncate, value in low 16
    union { float f; unsigned int i; } v;
    v.f = f;
    return v.i >> 16;
}

// ---------------------------------------------------------------------------
// Kernel 1 (prep, single launch): z=0..3 transpose+cvt the 4 weight matrices;
// z=4 fills the RoPE (cos,sin) fp32 table; z=5..8 convert x fp32->bf16.
// ---------------------------------------------------------------------------
__global__ __launch_bounds__(256) void prep(
    const float* __restrict__ x, u16* __restrict__ xb,
    const float* __restrict__ w0, const float* __restrict__ w1,
    const float* __restrict__ w2, const float* __restrict__ w3,
    u16* __restrict__ t0, u16* __restrict__ t1,
    u16* __restrict__ t2, u16* __restrict__ t3,
    float2* __restrict__ tab)
{
    int tx = threadIdx.x, ty = threadIdx.y;              // (32, 8)
    int tid = ty * 32 + tx;
    int z = blockIdx.z;
    if (z == 4) {
        int bidx = blockIdx.y * 32 + blockIdx.x;
        if (bidx < 256) {
            int idx = bidx * 256 + tid;                  // 0..65535
            int pos = idx >> 5, pi = idx & 31;
            const float l2_10000_over_32 = 0.41524101186f;   // log2(10000)/32
            float ang = (float)pos *
                __builtin_amdgcn_exp2f(-(float)pi * l2_10000_over_32);
            float sn, cs;
            __sincosf(ang, &sn, &cs);
            tab[idx] = make_float2(cs, sn);
        }
        return;
    }
    if (z >= 5) {
        int i = (((z - 5) * 1024 + blockIdx.y * 32 + blockIdx.x) * 256 + tid) * 4;
        float4 v = *(const float4*)(x + i);
        ushort4 o;
        o.x = f2bf(v.x); o.y = f2bf(v.y); o.z = f2bf(v.z); o.w = f2bf(v.w);
        *(ushort4*)(xb + i) = o;
        return;
    }
    __shared__ u16 tile[32][33];
    const float* src; u16* dst;
    switch (z) {
        case 0:  src = w0; dst = t0; break;
        case 1:  src = w1; dst = t1; break;
        case 2:  src = w2; dst = t2; break;
        default: src = w3; dst = t3; break;
    }
    int c0 = blockIdx.x * 32, r0 = blockIdx.y * 32;
    #pragma unroll
    for (int i = 0; i < 4; i++)
        tile[ty + i * 8][tx] = f2bf(src[(size_t)(r0 + ty + i * 8) * 1024 + c0 + tx]);
    __syncthreads();
    #pragma unroll
    for (int i = 0; i < 4; i++)
        dst[(size_t)(c0 + ty + i * 8) * 1024 + r0 + tx] = tile[tx][ty + i * 8];
}

// ---------------------------------------------------------------------------
// Kernel 2a: fused QKV GEMM, BK=64. A: 4096x1024 bf16 (x), Bt: 3072x1024
// stacked [Wq^T; Wk^T; Wv^T]. Q/K epilogue: table RoPE. V epilogue: LDS-bounce
// transpose, direct VT[bh][64][2048] write. Q scaled 1/sqrt(1024)*log2(e).
// ---------------------------------------------------------------------------
__global__ __launch_bounds__(256) void gemm_qkv(
    const u16* __restrict__ A, const u16* __restrict__ Bt,
    const float2* __restrict__ ropetab,
    u16* __restrict__ Qb, u16* __restrict__ Kb, u16* __restrict__ VT)
{
    __shared__ __align__(16) char smem[128 * 136 * 2];  // 34 KB pool
    u16* As = (u16*)smem;                                // 128x64 (16 KB)
    u16* Bs = (u16*)(smem + 16384);                      // 128x64 (16 KB)

    const int tid  = threadIdx.x;
    const int lane = tid & 63;
    const int wid  = tid >> 6;
    const int quad = lane >> 4;
    const int l15  = lane & 15;
    const int wm   = wid >> 1, wn = wid & 1;

    const int m0 = blockIdx.y * 128;
    const int n0 = blockIdx.x * 128;          // 0..2944, global stacked col
    const int mat = n0 >> 10;                 // 0=Q 1=K 2=V
    const int ln0 = n0 & 1023;                // col within that matrix

    f32x4 acc[4][4] = {};

    for (int k0 = 0; k0 < 1024; k0 += 64) {
        #pragma unroll
        for (int it = 0; it < 4; it++) {
            int c   = it * 256 + tid;                // chunk 0..1023 (16B each)
            int row = c >> 3;
            int col = ((c & 7) ^ (row & 7)) * 8;     // swizzled source chunk
            u16* lbA = &As[(size_t)(it * 256 + wid * 64) * 8];
            u16* lbB = &Bs[(size_t)(it * 256 + wid * 64) * 8];
            gl2lds16(&A [(size_t)(m0 + row) * 1024 + k0 + col], lbA);
            gl2lds16(&Bt[(size_t)(n0 + row) * 1024 + k0 + col], lbB);
        }
        __syncthreads();

        #pragma unroll
        for (int s = 0; s < 2; s++) {            // two K=32 steps within BK=64
            short8 a[4], b[4];
            #pragma unroll
            for (int i = 0; i < 4; i++) {
                int ra = wm * 64 + i * 16 + l15;
                int rb = wn * 64 + i * 16 + l15;
                a[i] = *(const short8*)(&As[ra * 64 + (((s * 4 + quad) ^ (ra & 7)) * 8)]);
                b[i] = *(const short8*)(&Bs[rb * 64 + (((s * 4 + quad) ^ (rb & 7)) * 8)]);
            }
            #pragma unroll
            for (int i = 0; i < 4; i++)
                #pragma unroll
                for (int j = 0; j < 4; j++)
                    acc[i][j] = __builtin_amdgcn_mfma_f32_16x16x32_bf16(a[i], b[j], acc[i][j], 0, 0, 0);
        }
        __syncthreads();
    }

    if (mat < 2) {
        u16* C = (mat == 0) ? Qb : Kb;
        const float scale = (mat == 0) ? (0.03125f * 1.44269504f) : 1.0f;
        const int odd = l15 & 1;
        #pragma unroll
        for (int i = 0; i < 4; i++)
            #pragma unroll
            for (int j = 0; j < 4; j++)
                #pragma unroll
                for (int r = 0; r < 4; r++) {
                    int lrow = wm * 64 + i * 16 + quad * 4 + r;
                    int col  = ln0 + wn * 64 + j * 16 + l15;
                    int pos  = (m0 + lrow) & 2047;
                    float v  = acc[i][j][r] * scale;
                    float vp = __shfl_xor(v, 1);     // partner column
                    float2 sc = ropetab[pos * 32 + ((col & 63) >> 1)];
                    float outv = odd ? (v * sc.x + vp * sc.y)
                                     : (v * sc.x - vp * sc.y);
                    C[(size_t)(m0 + lrow) * 1024 + col] = f2bf(outv);
                }
    } else {
        // V: bounce through LDS transposed, then coalesced writes to VT.
        u16* T = (u16*)smem;                    // 128 cols x 136 (pad) rows
        __syncthreads();                        // all waves done with As/Bs
        #pragma unroll
        for (int i = 0; i < 4; i++)
            #pragma unroll
            for (int j = 0; j < 4; j++)
                #pragma unroll
                for (int r = 0; r < 4; r++) {
                    int lrow = wm * 64 + i * 16 + quad * 4 + r;
                    int lcol = wn * 64 + j * 16 + l15;
                    T[lcol * 136 + lrow] = f2bf(acc[i][j][r]);
                }
        __syncthreads();
        int bb2 = m0 >> 11, pos0 = m0 & 2047;
        #pragma unroll
        for (int itc = 0; itc < 8; itc++) {
            int c  = itc * 256 + tid;           // 0..2047 chunks of 8 u16
            int ch = c >> 4;                    // 0..127 (2 heads x 64 ch)
            int px = (c & 15) * 8;
            int head = (ln0 + ch) >> 6;
            size_t dst = ((size_t)(bb2 * 16 + head) * 64 + (ch & 63)) * 2048
                         + pos0 + px;
            *(uint4*)(&VT[dst]) = *(const uint4*)(&T[ch * 136 + px]);
        }
    }
}

// ---------------------------------------------------------------------------
// Kernel 2b: out-projection GEMM, BK=64, fp32 output to d_out.
// ---------------------------------------------------------------------------
__global__ __launch_bounds__(256) void gemm_out(
    const u16* __restrict__ A, const u16* __restrict__ Bt, float* __restrict__ C)
{
    __shared__ __align__(16) u16 As[128 * 64];
    __shared__ __align__(16) u16 Bs[128 * 64];

    const int tid  = threadIdx.x;
    const int lane = tid & 63;
    const int wid  = tid >> 6;
    const int quad = lane >> 4;
    const int l15  = lane & 15;
    const int wm   = wid >> 1, wn = wid & 1;

    const int m0 = blockIdx.y * 128;
    const int n0 = blockIdx.x * 128;

    f32x4 acc[4][4] = {};

    for (int k0 = 0; k0 < 1024; k0 += 64) {
        #pragma unroll
        for (int it = 0; it < 4; it++) {
            int c   = it * 256 + tid;
            int row = c >> 3;
            int col = ((c & 7) ^ (row & 7)) * 8;
            u16* lbA = &As[(size_t)(it * 256 + wid * 64) * 8];
            u16* lbB = &Bs[(size_t)(it * 256 + wid * 64) * 8];
            gl2lds16(&A [(size_t)(m0 + row) * 1024 + k0 + col], lbA);
            gl2lds16(&Bt[(size_t)(n0 + row) * 1024 + k0 + col], lbB);
        }
        __syncthreads();

        #pragma unroll
        for (int s = 0; s < 2; s++) {
            short8 a[4], b[4];
            #pragma unroll
            for (int i = 0; i < 4; i++) {
                int ra = wm * 64 + i * 16 + l15;
                int rb = wn * 64 + i * 16 + l15;
                a[i] = *(const short8*)(&As[ra * 64 + (((s * 4 + quad) ^ (ra & 7)) * 8)]);
                b[i] = *(const short8*)(&Bs[rb * 64 + (((s * 4 + quad) ^ (rb & 7)) * 8)]);
            }
            #pragma unroll
            for (int i = 0; i < 4; i++)
                #pragma unroll
                for (int j = 0; j < 4; j++)
                    acc[i][j] = __builtin_amdgcn_mfma_f32_16x16x32_bf16(a[i], b[j], acc[i][j], 0, 0, 0);
        }
        __syncthreads();
    }

    #pragma unroll
    for (int i = 0; i < 4; i++)
        #pragma unroll
        for (int j = 0; j < 4; j++)
            #pragma unroll
            for (int r = 0; r < 4; r++) {
                int row = m0 + wm * 64 + i * 16 + quad * 4 + r;
                int col = n0 + wn * 64 + j * 16 + l15;
                C[(size_t)row * 1024 + col] = acc[i][j][r];
            }
}

// ---------------------------------------------------------------------------
// Kernel 4: flash attention v8 — 32x32x16 MFMA + S^T trick (LDS-issue fix).
//  v7 was LDS-issue bound: 36 b128 + 32 scalar b16 stores per wave-tile for
//  16 q-rows (~618 LDS cyc vs 154 MFMA cyc) -> ~66 us floor = measured wall.
//  v8: wave owns 32 q-rows via 32x32 MFMAs (2x FLOP per fragment read), and
//  computes S^T = K*Q^T so (a) P packs into 16 ds_write_b64 (4 consecutive
//  keys per reg group), (b) P lands row-major [qrow][key] -> PV A-frags are
//  contiguous b128, (c) row-sum needs one shfl_xor(32).
//  Per wave-tile: 40 b128 + 16 b64 for 2x rows -> LDS floor ~31 us.
//  LDS 50 KB (Ks 16 + VTs 16 + Ps 4x32x72), 256 thr, ~130 VGPR.
// ---------------------------------------------------------------------------
__global__ __launch_bounds__(256) void attn(
    const u16* __restrict__ Q, const u16* __restrict__ Kb,
    const u16* __restrict__ VT, u16* __restrict__ Y)
{
    __shared__ __align__(16) u16 Ks [128 * 64];   // row=key, 8 chunks ^(r&7)
    __shared__ __align__(16) u16 VTs[64 * 128];   // row=ch, 16 chunks ^(r&15)
    __shared__ __align__(16) u16 Ps [4][32 * 72]; // per-wave [qrow][key(64)+pad]

    const int tid  = threadIdx.x;
    const int lane = tid & 63, wid = tid >> 6;    // wid 0..3
    const int l31  = lane & 31, hi = lane >> 5;   // hi = 0/1

    const int bh = blockIdx.x;        // 0..31  (XCD-locality: fast axis)
    const int qt = blockIdx.y;        // 0..15, 128 q-rows each
    const int bb = bh >> 4, h = bh & 15;

    const size_t base = ((size_t)bb * 2048) * 1024 + (size_t)h * 64;

    // Q B-fragments (B[n=qrow][k=ch]: n = lane&31, ch = hi*8 + j + 16s)
    short8 qf[4];
    {
        const u16* qp = Q + base
                      + ((size_t)qt * 128 + wid * 32 + l31) * 1024 + hi * 8;
        #pragma unroll
        for (int s = 0; s < 4; s++)
            qf[s] = *(const short8*)(qp + s * 16);
    }

    f32x16 o0 = {}, o1 = {};
    float lsum = 0.0f;

    for (int j0 = 0; j0 < 2048; j0 += 128) {
        __syncthreads();   // prior tile's fragment reads complete
        #pragma unroll
        for (int it = 0; it < 4; it++) {
            int c = it * 256 + tid;                       // chunk 0..1023
            int rk = c >> 3, ck = ((c & 7)  ^ (rk & 7))  * 8;   // K: 128x64
            int rv = c >> 4, cv = ((c & 15) ^ (rv & 15)) * 8;   // V: 64x128
            u16* lbK = &Ks [(size_t)(it * 256 + wid * 64) * 8];
            u16* lbV = &VTs[(size_t)(it * 256 + wid * 64) * 8];
            gl2lds16(&Kb[base + (size_t)(j0 + rk) * 1024 + ck], lbK);
            gl2lds16(&VT[((size_t)bh * 64 + rv) * 2048 + j0 + cv], lbV);
        }
        __syncthreads();   // drain DMA

        // S^T = K * Q^T: 4 stripes of 32 keys. A = K-frag (m=key lane&31,
        // ch = hi*8+16s), B = Q-frag (regs). C col = qrow, row = key.
        f32x16 st[4];
        #pragma unroll
        for (int t = 0; t < 4; t++) {
            int key = t * 32 + l31;
            f32x16 z = {};
            #pragma unroll
            for (int s = 0; s < 4; s++) {
                int chunk = ((2 * s + hi) ^ (key & 7)) * 8;
                short8 kf = *(const short8*)(&Ks[key * 64 + chunk]);
                z = __builtin_amdgcn_mfma_f32_32x32x16_bf16(kf, qf[s], z, 0, 0, 0);
            }
            st[t] = z;
        }

        // softmax + PV per 64-key half (Ps stripe reused across halves)
        u16* ps = Ps[wid];
        #pragma unroll
        for (int hh = 0; hh < 2; hh++) {
            #pragma unroll
            for (int tt = 0; tt < 2; tt++) {
                int t = hh * 2 + tt;
                #pragma unroll
                for (int g = 0; g < 4; g++) {
                    // regs 4g..4g+3 = keys (t*32 + g*8 + hi*4) + 0..3
                    float p0 = __builtin_amdgcn_exp2f(st[t][4 * g + 0]);
                    float p1 = __builtin_amdgcn_exp2f(st[t][4 * g + 1]);
                    float p2 = __builtin_amdgcn_exp2f(st[t][4 * g + 2]);
                    float p3 = __builtin_amdgcn_exp2f(st[t][4 * g + 3]);
                    lsum += (p0 + p1) + (p2 + p3);
                    uint2 w;
                    w.x = f2bf_trunc_u32(p0) | (f2bf_trunc_u32(p1) << 16);
                    w.y = f2bf_trunc_u32(p2) | (f2bf_trunc_u32(p3) << 16);
                    int lk = tt * 32 + g * 8 + hi * 4;    // key within half
                    *(uint2*)(&ps[l31 * 72 + lk]) = w;
                }
            }
            // wave-local RAW fence (DS in-order per wave; stop compiler hoist)
            asm volatile("s_waitcnt lgkmcnt(0)" ::: "memory");

            // PV: O[qrow][ch] += P * V.  A = P-frag [m=qrow][k=key],
            // B = V-frag [k=key][n=ch] from VTs[ch][key].
            #pragma unroll
            for (int s = 0; s < 4; s++) {
                int koff = s * 16 + hi * 8;               // key within half
                short8 pf = *(const short8*)(&ps[l31 * 72 + koff]);
                int kch = hh * 8 + 2 * s + hi;            // key chunk in tile
                short8 v0 = *(const short8*)(&VTs[l31 * 128 + ((kch ^ (l31 & 15)) * 8)]);
                short8 v1 = *(const short8*)(&VTs[(32 + l31) * 128 + ((kch ^ ((32 + l31) & 15)) * 8)]);
                o0 = __builtin_amdgcn_mfma_f32_32x32x16_bf16(pf, v0, o0, 0, 0, 0);
                o1 = __builtin_amdgcn_mfma_f32_32x32x16_bf16(pf, v1, o1, 0, 0, 0);
            }
            // keep next half's stores after these reads
            asm volatile("" ::: "memory");
        }
    }

    // row-sum: lane holds all partials for qrow = lane&31 (S^T col) ->
    // one cross-half reduce, then broadcast per-reg via shfl.
    lsum += __shfl_xor(lsum, 32);
    float linv = 1.0f / lsum;

    size_t qrow0 = (size_t)qt * 128 + wid * 32;
    #pragma unroll
    for (int half = 0; half < 2; half++) {
        f32x16 o = half ? o1 : o0;
        #pragma unroll
        for (int reg = 0; reg < 16; reg++) {
            int qrow = (reg & 3) + 8 * (reg >> 2) + 4 * hi;   // C/D row (m74)
            float nv = o[reg] * __shfl(linv, qrow);
            Y[base + (qrow0 + qrow) * 1024 + half * 32 + l31] = f2bf(nv);
        }
    }
}

// ---------------------------------------------------------------------------
extern "C" void kernel_launch(void* const* d_in, const int* in_sizes, int n_in,
                              void* d_out, int out_size, void* d_ws, size_t ws_size,
                              hipStream_t stream)
{
    const float* x  = (const float*)d_in[0];
    const float* Wq = (const float*)d_in[1];
    const float* Wk = (const float*)d_in[2];
    const float* Wv = (const float*)d_in[3];
    const float* Wo = (const float*)d_in[4];
    float* out = (float*)d_out;

    char* ws = (char*)d_ws;
    u16*    xb    = (u16*)   (ws + (0ull  << 20));   // 8 MB
    u16*    WqkvT = (u16*)   (ws + (8ull  << 20));   // 6 MB stacked
    u16*    WoT   = (u16*)   (ws + (14ull << 20));   // 2 MB
    u16*    Qb    = (u16*)   (ws + (16ull << 20));   // 8 MB each
    u16*    Kb    = (u16*)   (ws + (24ull << 20));
    u16*    VTb   = (u16*)   (ws + (32ull << 20));   // V transposed per head
    u16*    Yb    = (u16*)   (ws + (40ull << 20));
    float2* tab   = (float2*)(ws + (48ull << 20));   // 512 KB rope table

    prep<<<dim3(32, 32, 9), dim3(32, 8), 0, stream>>>(
        x, xb, Wq, Wk, Wv, Wo,
        WqkvT, WqkvT + (1024ull * 1024), WqkvT + (2048ull * 1024), WoT, tab);
    gemm_qkv<<<dim3(24, 32), 256, 0, stream>>>(xb, WqkvT, tab, Qb, Kb, VTb);
    attn<<<dim3(32, 16), 256, 0, stream>>>(Qb, Kb, VTb, Yb);
    gemm_out<<<dim3(8, 32), 256, 0, stream>>>(Yb, WoT, out);
}